// Round 5
// baseline (327.663 us; speedup 1.0000x reference)
//
#include <hip/hip_runtime.h>
#include <cstdint>
#include <cstddef>

// Problem constants
#define BB   8
#define TT   4096
#define DD   512
#define UU   512
#define NN   1536   // 3*UU
#define KK   1024   // 2*DD
#define MM   32768  // BB*TT
#define NCH  256    // number of scan chunks
#define CHL  16     // chunk length (NCH*CHL == TT)

using bf16x8 = __attribute__((ext_vector_type(8))) __bf16;
using f32x4  = __attribute__((ext_vector_type(4))) float;
using us8    = __attribute__((ext_vector_type(8))) unsigned short;

__device__ __forceinline__ unsigned short f2bf(float f) {
    unsigned u = __float_as_uint(f);
    u += 0x7fffu + ((u >> 16) & 1u);   // RTNE
    return (unsigned short)(u >> 16);
}
__device__ __forceinline__ float bf2f(unsigned short s) {
    return __uint_as_float(((unsigned)s) << 16);
}
__device__ __forceinline__ float sigf(float x) { return 1.0f / (1.0f + __expf(-x)); }
__device__ __forceinline__ float tanh_(float x) { return 1.0f - 2.0f / (1.0f + __expf(2.0f * x)); }

__device__ __forceinline__ void async16(const void* g, void* l) {
    __builtin_amdgcn_global_load_lds(
        (__attribute__((address_space(1))) void*)g,
        (__attribute__((address_space(3))) void*)l, 16, 0, 0);
}

// ---- 1) prep: pad+convert x -> xpad (bf16, 16B/lane), transpose kern -> kT ----
__global__ void k_prep(const float* __restrict__ x, unsigned short* __restrict__ xpad,
                       const float* __restrict__ kern, unsigned short* __restrict__ kT) {
    int bx = blockIdx.x;
    int by = blockIdx.y;
    int tid = threadIdx.x;
    if (bx < 1025) {
        int q = bx * 256 + tid;              // oct index within batch
        if (q >= 4097 * 64) return;
        int tp = q >> 6;                     // 0..4096
        int d  = (q & 63) << 3;              // 0..504
        size_t oi = ((size_t)by * 4097 + tp) * 512 + d;
        us8 o;
        if (tp == 0) {
            o = (us8)0;
        } else {
            const float* src = x + ((size_t)by * 4096 + (tp - 1)) * 512 + d;
            float4 v0 = *(const float4*)(src);
            float4 v1 = *(const float4*)(src + 4);
            o[0] = f2bf(v0.x); o[1] = f2bf(v0.y); o[2] = f2bf(v0.z); o[3] = f2bf(v0.w);
            o[4] = f2bf(v1.x); o[5] = f2bf(v1.y); o[6] = f2bf(v1.z); o[7] = f2bf(v1.w);
        }
        *(us8*)(xpad + oi) = o;
    } else {
        __shared__ float tile[32][33];
        int idx = (bx - 1025) * 8 + by;      // 0..191
        int c  = tid & 31;
        int r0 = tid >> 5;                   // 0..7
        for (int t8 = 0; t8 < 8; ++t8) {
            int tnum = idx * 8 + t8;         // 0..1535
            int k0 = (tnum & 31) * 32;       // 32 K-tiles
            int n0 = (tnum >> 5) * 32;       // 48 N-tiles
#pragma unroll
            for (int rr = r0; rr < 32; rr += 8)
                tile[rr][c] = kern[(size_t)(k0 + rr) * NN + n0 + c];
            __syncthreads();
#pragma unroll
            for (int rr = r0; rr < 32; rr += 8)
                kT[(size_t)(n0 + rr) * KK + k0 + c] = f2bf(tile[c][rr]);
            __syncthreads();
        }
    }
}

// ---- 2) GEMM: gates[m][n] = A[m][:] * kT[n][:]^T + bias[n], stored bf16 ----
__global__ __launch_bounds__(256) void k_gemm(
    const unsigned short* __restrict__ xpad,
    const unsigned short* __restrict__ kT,
    const float* __restrict__ bias,
    unsigned short* __restrict__ gates)
{
    __shared__ unsigned short As[128 * 64];
    __shared__ unsigned short Bs[128 * 64];
    const int tid  = threadIdx.x;
    const int bi   = blockIdx.x;
    const int xcd  = bi & 7;
    const int loc  = bi >> 3;            // 0..383
    const int mt   = xcd * 32 + loc / 12;
    const int nt   = loc % 12;
    const int m0   = mt * 128;
    const int n0   = nt * 128;
    const int boff = m0 >> 12;           // batch index of the whole tile
    const size_t abase = (size_t)(m0 + boff) * 512;

    f32x4 acc[4][4] = {};

    const int wid  = tid >> 6;
    const int lane = tid & 63;
    const int wm   = (wid & 1) * 64;
    const int wn   = (wid >> 1) * 64;
    const int lrow = lane & 15;
    const int quad = lane >> 4;

    for (int kk = 0; kk < KK; kk += 64) {
#pragma unroll
        for (int q = 0; q < 4; ++q) {
            int L   = q * 256 + tid;
            int row = L >> 3;
            int sp  = L & 7;
            int sl  = sp ^ (row & 7);
            async16(xpad + abase + (size_t)row * 512 + kk + sl * 8, As + (size_t)L * 8);
            async16(kT + (size_t)(n0 + row) * KK + kk + sl * 8, Bs + (size_t)L * 8);
        }
        __syncthreads();
#pragma unroll
        for (int ks = 0; ks < 2; ++ks) {
            bf16x8 af[4], bfr[4];
#pragma unroll
            for (int i = 0; i < 4; ++i) {
                int row = wm + i * 16 + lrow;
                int sp  = (ks * 4 + quad) ^ (row & 7);
                af[i] = *(const bf16x8*)(As + row * 64 + sp * 8);
            }
#pragma unroll
            for (int j = 0; j < 4; ++j) {
                int row = wn + j * 16 + lrow;
                int sp  = (ks * 4 + quad) ^ (row & 7);
                bfr[j] = *(const bf16x8*)(Bs + row * 64 + sp * 8);
            }
#pragma unroll
            for (int i = 0; i < 4; ++i)
#pragma unroll
                for (int j = 0; j < 4; ++j)
                    acc[i][j] = __builtin_amdgcn_mfma_f32_16x16x32_bf16(af[i], bfr[j], acc[i][j], 0, 0, 0);
        }
        __syncthreads();
    }

#pragma unroll
    for (int j = 0; j < 4; ++j) {
        int col  = n0 + wn + j * 16 + lrow;
        float bv = bias[col];
#pragma unroll
        for (int i = 0; i < 4; ++i) {
            int rbase = m0 + wm + i * 16 + quad * 4;
#pragma unroll
            for (int r = 0; r < 4; ++r) {
                gates[(size_t)(rbase + r) * NN + col] = f2bf(acc[i][j][r] + bv);
            }
        }
    }
}

// ---- 3) pass A: wave-per-chunk local scan + f-product, 16B loads ----
// block = 256 threads = 4 waves = 4 chunks; lane owns 8 units.
__global__ __launch_bounds__(256) void k_scanA(const unsigned short* __restrict__ gates,
                        float* __restrict__ Fp, float* __restrict__ Ce) {
    const int wave  = threadIdx.x >> 6;
    const int lane  = threadIdx.x & 63;
    const int chunk = blockIdx.x * 4 + wave;   // 0..255
    const int b     = blockIdx.y;              // 0..7
    const int u     = lane << 3;               // 8 units/lane
    const size_t g0 = ((size_t)b * TT + (size_t)chunk * CHL) * NN + u;

    float c[8] = {0, 0, 0, 0, 0, 0, 0, 0};
    float F[8] = {1, 1, 1, 1, 1, 1, 1, 1};

    us8 bz[4], bf_[4];
#pragma unroll
    for (int j = 0; j < 4; ++j) {
        bz[j]  = *(const us8*)(gates + g0 + (size_t)j * NN);
        bf_[j] = *(const us8*)(gates + g0 + (size_t)j * NN + UU);
    }
#pragma unroll
    for (int k = 0; k < 4; ++k) {
        us8 nz[4], nf[4];
        if (k < 3) {
#pragma unroll
            for (int j = 0; j < 4; ++j) {
                size_t gg = g0 + (size_t)((k + 1) * 4 + j) * NN;
                nz[j] = *(const us8*)(gates + gg);
                nf[j] = *(const us8*)(gates + gg + UU);
            }
        }
#pragma unroll
        for (int j = 0; j < 4; ++j) {
#pragma unroll
            for (int e = 0; e < 8; ++e) {
                float f = sigf(bf2f(bf_[j][e]));
                float z = tanh_(bf2f(bz[j][e]));
                c[e] = f * c[e] + (1.0f - f) * z;
                F[e] *= f;
            }
        }
        if (k < 3) {
#pragma unroll
            for (int j = 0; j < 4; ++j) { bz[j] = nz[j]; bf_[j] = nf[j]; }
        }
    }
    size_t ci = ((size_t)b * NCH + chunk) * UU + u;
    *(f32x4*)(Fp + ci)     = f32x4{F[0], F[1], F[2], F[3]};
    *(f32x4*)(Fp + ci + 4) = f32x4{F[4], F[5], F[6], F[7]};
    *(f32x4*)(Ce + ci)     = f32x4{c[0], c[1], c[2], c[3]};
    *(f32x4*)(Ce + ci + 4) = f32x4{c[4], c[5], c[6], c[7]};
}

// ---- 4) pass B: sequential scan over chunks -> carry-in per chunk ----
__global__ __launch_bounds__(128) void k_scanB(const float* __restrict__ Fp,
                        const float* __restrict__ Ce, float* __restrict__ Cin) {
    int gid = blockIdx.x * 128 + threadIdx.x;   // 0..4095
    int bb = gid >> 9;           // batch
    int uu = gid & 511;          // unit
    size_t base = (size_t)bb * NCH * UU + uu;
    float c = 0.0f;
    for (int k0 = 0; k0 < NCH; k0 += 8) {
        float F[8], E[8];
#pragma unroll
        for (int j = 0; j < 8; ++j) {
            F[j] = Fp[base + (size_t)(k0 + j) * UU];
            E[j] = Ce[base + (size_t)(k0 + j) * UU];
        }
#pragma unroll
        for (int j = 0; j < 8; ++j) {
            Cin[base + (size_t)(k0 + j) * UU] = c;
            c = F[j] * c + E[j];
        }
    }
}

// ---- 5) pass C: wave-per-chunk replay with true carry, out = o*c, 16B loads ----
__global__ __launch_bounds__(256) void k_scanC(const unsigned short* __restrict__ gates,
                        const float* __restrict__ Cin, float* __restrict__ out) {
    const int wave  = threadIdx.x >> 6;
    const int lane  = threadIdx.x & 63;
    const int chunk = blockIdx.x * 4 + wave;
    const int b     = blockIdx.y;
    const int u     = lane << 3;
    const size_t g0 = ((size_t)b * TT + (size_t)chunk * CHL) * NN + u;
    size_t o = ((size_t)b * TT + (size_t)chunk * CHL) * UU + u;

    size_t ci = ((size_t)b * NCH + chunk) * UU + u;
    float c[8];
    {
        f32x4 cv0 = *(const f32x4*)(Cin + ci);
        f32x4 cv1 = *(const f32x4*)(Cin + ci + 4);
        c[0] = cv0[0]; c[1] = cv0[1]; c[2] = cv0[2]; c[3] = cv0[3];
        c[4] = cv1[0]; c[5] = cv1[1]; c[6] = cv1[2]; c[7] = cv1[3];
    }

    us8 bz[4], bf_[4], bo[4];
#pragma unroll
    for (int j = 0; j < 4; ++j) {
        bz[j]  = *(const us8*)(gates + g0 + (size_t)j * NN);
        bf_[j] = *(const us8*)(gates + g0 + (size_t)j * NN + UU);
        bo[j]  = *(const us8*)(gates + g0 + (size_t)j * NN + 2 * UU);
    }
#pragma unroll
    for (int k = 0; k < 4; ++k) {
        us8 nz[4], nf[4], no[4];
        if (k < 3) {
#pragma unroll
            for (int j = 0; j < 4; ++j) {
                size_t gg = g0 + (size_t)((k + 1) * 4 + j) * NN;
                nz[j] = *(const us8*)(gates + gg);
                nf[j] = *(const us8*)(gates + gg + UU);
                no[j] = *(const us8*)(gates + gg + 2 * UU);
            }
        }
#pragma unroll
        for (int j = 0; j < 4; ++j) {
            float y[8];
#pragma unroll
            for (int e = 0; e < 8; ++e) {
                float f  = sigf(bf2f(bf_[j][e]));
                float z  = tanh_(bf2f(bz[j][e]));
                float og = sigf(bf2f(bo[j][e]));
                c[e] = f * c[e] + (1.0f - f) * z;
                y[e] = og * c[e];
            }
            f32x4 y0 = {y[0], y[1], y[2], y[3]};
            f32x4 y1 = {y[4], y[5], y[6], y[7]};
            __builtin_nontemporal_store(y0, (f32x4*)(out + o));
            __builtin_nontemporal_store(y1, (f32x4*)(out + o + 4));
            o += UU;
        }
        if (k < 3) {
#pragma unroll
            for (int j = 0; j < 4; ++j) { bz[j] = nz[j]; bf_[j] = nf[j]; bo[j] = no[j]; }
        }
    }
}

extern "C" void kernel_launch(void* const* d_in, const int* in_sizes, int n_in,
                              void* d_out, int out_size, void* d_ws, size_t ws_size,
                              hipStream_t stream) {
    const float* x    = (const float*)d_in[0];
    const float* kern = (const float*)d_in[1];
    const float* bias = (const float*)d_in[2];
    float* out = (float*)d_out;
    char* ws = (char*)d_ws;

    // workspace layout (bytes)
    unsigned short* xpad  = (unsigned short*)(ws + 0);           // 8*4097*512*2   = 33,562,624
    unsigned short* kT    = (unsigned short*)(ws + 33562624);    // 1536*1024*2    =  3,145,728
    unsigned short* gates = (unsigned short*)(ws + 36708352);    // 32768*1536*2   = 100,663,296
    float* Fp  = (float*)(ws + 137371648);                       // 8*256*512*4    =  4,194,304
    float* Ce  = (float*)(ws + 141565952);                       //                =  4,194,304
    float* Cin = (float*)(ws + 145760256);                       //                =  4,194,304
    // total: 149,954,560 bytes

    hipLaunchKernelGGL(k_prep,  dim3(1025 + 24, 8), dim3(256), 0, stream, x, xpad, kern, kT);
    hipLaunchKernelGGL(k_gemm,  dim3(3072),         dim3(256), 0, stream, xpad, kT, bias, gates);
    hipLaunchKernelGGL(k_scanA, dim3(NCH / 4, BB),  dim3(256), 0, stream, gates, Fp, Ce);
    hipLaunchKernelGGL(k_scanB, dim3(32),           dim3(128), 0, stream, Fp, Ce, Cin);
    hipLaunchKernelGGL(k_scanC, dim3(NCH / 4, BB),  dim3(256), 0, stream, gates, Cin, out);
}